// Round 6
// baseline (483.526 us; speedup 1.0000x reference)
//
#include <hip/hip_runtime.h>
#include <hip/hip_fp16.h>
#include <stdint.h>

#define BATCH 32768
#define NE    8192
#define DIM   256
#define LOSS_OFF 8388608     // 32768*256
#define IDX_OFF  8388609
#define KBIAS  768.0f        // keeps key = cn+KBIAS-2dot strictly positive
#define MARGIN 0.5f          // > 2*maxerr(0.16) + trunc(0.125)

typedef _Float16 v8h  __attribute__((ext_vector_type(8)));
typedef _Float16 v4h  __attribute__((ext_vector_type(4)));
typedef float    f32x4 __attribute__((ext_vector_type(4)));
typedef unsigned long long ull;

// async global->LDS, 16B per lane; LDS dest = wave-uniform base + lane*16
#define GLOAD_LDS16(g, l) __builtin_amdgcn_global_load_lds( \
    (const __attribute__((address_space(1))) void*)(g),     \
    (__attribute__((address_space(3))) void*)(l), 16, 0, 0)

// ---- ws layout (bytes) ----
// Ahi  f16 [BATCH][256] @ 0         (16777216)
// Bhi  f16 [NE][256]    @ 16777216  ( 4194304)
// cn   f32 [NE]         @ 20971520  (   32768)
// xn   f32 [BATCH]      @ 21004288  (  131072)
// bidx i32 [BATCH]      @ 21135360  (  131072)
// cand u32 [BATCH][48]  @ 21266432  ( 6291456)  total ~27.6 MB

// ---------------- prep: x -> hi f16, row norms, loss zero ----------------
__global__ __launch_bounds__(256) void vq_prep_x(
    const float* __restrict__ x, _Float16* __restrict__ Ahi,
    float* __restrict__ xn, float* __restrict__ out) {
  const int w = threadIdx.x >> 6, lane = threadIdx.x & 63;
  const int row = blockIdx.x * 4 + w;
  const float4 v = *(const float4*)(x + (size_t)row * DIM + (lane << 2));
  v4h h = { (_Float16)v.x, (_Float16)v.y, (_Float16)v.z, (_Float16)v.w };
  *(v4h*)(Ahi + (size_t)row * DIM + (lane << 2)) = h;
  float s = v.x * v.x + v.y * v.y + v.z * v.z + v.w * v.w;
  #pragma unroll
  for (int off = 32; off > 0; off >>= 1) s += __shfl_down(s, off);
  if (lane == 0) xn[row] = s;
  if (row == 0 && lane == 0) out[LOSS_OFF] = 0.0f;
}

// ---------------- prep: c -> hi f16 + norms ----------------
__global__ __launch_bounds__(256) void vq_prep_c(
    const float* __restrict__ c, _Float16* __restrict__ Bhi,
    float* __restrict__ cn) {
  const int w = threadIdx.x >> 6, lane = threadIdx.x & 63;
  const int row = blockIdx.x * 4 + w;
  const float4 v = *(const float4*)(c + (size_t)row * DIM + (lane << 2));
  v4h h = { (_Float16)v.x, (_Float16)v.y, (_Float16)v.z, (_Float16)v.w };
  *(v4h*)(Bhi + (size_t)row * DIM + (lane << 2)) = h;
  float s = v.x * v.x + v.y * v.y + v.z * v.z + v.w * v.w;
  #pragma unroll
  for (int off = 32; off > 0; off >>= 1) s += __shfl_down(s, off);
  if (lane == 0) cn[row] = s;
}

// ---------------- stage 1: persistent GEMM + running per-lane top-3 ----
// grid=256 (1 block/CU), 4 waves, block owns 128 rows. A-rows in registers
// (loaded once). B streams: 64 tiles of 128 cols, full K=256, through a
// 2x64KB LDS dbuf in TRANSPOSED unit layout [u=k/8][col] (16B units) ->
// ds_read addresses contiguous per 16-lane group: conflict-free, imm-offset.
// Per (row, lane) keep running top-3 packed keys over the lane's 512 cols.
__global__ __launch_bounds__(256, 1) void vq_gemm_topk(
    const _Float16* __restrict__ A, const _Float16* __restrict__ B,
    const float* __restrict__ cn, unsigned* __restrict__ cand) {
  __shared__ _Float16 Bs[2][128 * 256];   // 2 x 64 KB

  const int tid = threadIdx.x, w = tid >> 6, lane = tid & 63;
  const int l15 = lane & 15, l4 = lane >> 4;
  const int rowBase = blockIdx.x * 128;
  const int wrow = w << 5;                 // wave owns 32 rows

  // ---- A fragments in registers: a[mi][ks], row = wrow+mi*16+l15, k = ks*32+l4*8
  v8h a[2][8];
  #pragma unroll
  for (int mi = 0; mi < 2; ++mi)
    #pragma unroll
    for (int ks = 0; ks < 8; ++ks)
      a[mi][ks] = *(const v8h*)(A + (size_t)(rowBase + wrow + mi * 16 + l15) * DIM
                                  + ks * 32 + l4 * 8);

  // ---- running top-3 per (mi,r): packed (key23|tile6|ni3), l15 = col&15
  unsigned k0[2][4], k1[2][4], k2[2][4];
  #pragma unroll
  for (int mi = 0; mi < 2; ++mi)
    #pragma unroll
    for (int r = 0; r < 4; ++r) { k0[mi][r] = k1[mi][r] = k2[mi][r] = 0xFFFFFFFFu; }

  // staging: inst j fills linear units (w*16+j)*64 + lane of [u][col] layout
  // u = w*8 + (j>>1), col = (j&1)*64 + lane
  auto STAGE = [&](int buf, int tile) {
    const _Float16* src = B + ((size_t)tile * 128 + lane) * DIM + w * 64;
    #pragma unroll
    for (int j = 0; j < 16; ++j)
      GLOAD_LDS16(src + (j & 1) * 16384 + (j >> 1) * 8,
                  &Bs[buf][(w * 16 + j) * 512]);
  };

  STAGE(0, 0);
  const int ldb = l4 * 1024 + l15 * 8;     // half-index base of b-frag reads

  #pragma unroll 1
  for (int t = 0; t < 64; ++t) {
    __syncthreads();                       // buf[t&1] staged; prev reads done
    const int cur = t & 1;
    STAGE(cur ^ 1, (t + 1) & 63);          // prefetch next (hidden under compute)

    float cnb[8];
    #pragma unroll
    for (int ni = 0; ni < 8; ++ni)
      cnb[ni] = cn[t * 128 + ni * 16 + l15] + KBIAS;

    f32x4 acc[2][8];
    #pragma unroll
    for (int mi = 0; mi < 2; ++mi)
      #pragma unroll
      for (int ni = 0; ni < 8; ++ni) acc[mi][ni] = (f32x4)0.0f;

    #pragma unroll
    for (int ks = 0; ks < 8; ++ks) {
      v8h b[8];
      #pragma unroll
      for (int ni = 0; ni < 8; ++ni)
        b[ni] = *(const v8h*)&Bs[cur][ks * 4096 + ldb + ni * 128];
      #pragma unroll
      for (int mi = 0; mi < 2; ++mi)
        #pragma unroll
        for (int ni = 0; ni < 8; ++ni)
          acc[mi][ni] = __builtin_amdgcn_mfma_f32_16x16x32_f16(
              a[mi][ks], b[ni], acc[mi][ni], 0, 0, 0);
    }

    // running top-3 insert (branchless, static indices)
    #pragma unroll
    for (int mi = 0; mi < 2; ++mi)
      #pragma unroll
      for (int ni = 0; ni < 8; ++ni)
        #pragma unroll
        for (int r = 0; r < 4; ++r) {
          const float d = fmaf(-2.0f, acc[mi][ni][r], cnb[ni]);   // >0 always
          const unsigned p = (__float_as_uint(d) & 0xFFFFFE00u)
                           | (unsigned)((t << 3) | ni);
          const bool b2 = p < k2[mi][r];
          const bool b1 = p < k1[mi][r];
          const bool b0 = p < k0[mi][r];
          k2[mi][r] = b2 ? (b1 ? k1[mi][r] : p) : k2[mi][r];
          k1[mi][r] = b1 ? (b0 ? k0[mi][r] : p) : k1[mi][r];
          k0[mi][r] = b0 ? p : k0[mi][r];
        }
  }

  // ---- store 48 candidates per row: cand[row][k*16 + l15]
  #pragma unroll
  for (int mi = 0; mi < 2; ++mi)
    #pragma unroll
    for (int r = 0; r < 4; ++r) {
      const size_t row = rowBase + wrow + mi * 16 + l4 * 4 + r;
      cand[row * 48 +      l15] = k0[mi][r];
      cand[row * 48 + 16 + l15] = k1[mi][r];
      cand[row * 48 + 32 + l15] = k2[mi][r];
    }
}

// ---------------- stage 2: per-row margin test + exact refine ----------------
__global__ __launch_bounds__(256) void vq_refine(
    const unsigned* __restrict__ cand, const float* __restrict__ x,
    const float* __restrict__ c, const float* __restrict__ xn,
    const float* __restrict__ cn, int* __restrict__ bestIdx) {
  const int w = threadIdx.x >> 6, lane = threadIdx.x & 63;
  const int row = blockIdx.x * 4 + w;
  const unsigned p = (lane < 48) ? cand[(size_t)row * 48 + lane] : 0xFFFFFFFFu;
  unsigned mn = p;
  #pragma unroll
  for (int off = 1; off < 64; off <<= 1) {
    const unsigned o = __shfl_xor(mn, off);
    if (o < mn) mn = o;
  }
  const float thr = __uint_as_float(mn & 0xFFFFFE00u) + MARGIN;
  const bool inm = (lane < 48) && (__uint_as_float(p & 0xFFFFFE00u) <= thr);
  const ull m = __ballot(inm);
  int winner;
  if (__popcll(m) == 1) {
    const int src = __ffsll((long long)m) - 1;
    winner = (int)(((mn >> 3) & 63) * 128 + (mn & 7) * 16 + (src & 15));
  } else {
    const float4 xv = *(const float4*)(x + (size_t)row * DIM + (lane << 2));
    const float xnr = xn[row];
    float bd = 3.4e38f; int bi = 0x7fffffff;
    ull mm = m;
    while (mm) {
      const int src = __ffsll((long long)mm) - 1; mm &= mm - 1;
      const unsigned pw = __shfl(p, src);
      const int idx = (int)(((pw >> 3) & 63) * 128 + (pw & 7) * 16 + (src & 15));
      const float4 cv = *(const float4*)(c + (size_t)idx * DIM + (lane << 2));
      float dsum = xv.x * cv.x + xv.y * cv.y + xv.z * cv.z + xv.w * cv.w;
      #pragma unroll
      for (int off = 1; off < 64; off <<= 1) dsum += __shfl_xor(dsum, off);
      const float d = xnr + cn[idx] - 2.0f * dsum;   // round-2-proven formula
      if (d < bd || (d == bd && idx < bi)) { bd = d; bi = idx; }
    }
    winner = bi;
  }
  if (lane == 0) bestIdx[row] = winner;
}

// ---------------- finish: gather + loss + index output ----------------
__global__ __launch_bounds__(256) void vq_finish(
    const float* __restrict__ x, const float* __restrict__ c,
    const int* __restrict__ bestIdx, float* __restrict__ out) {
  __shared__ float red[4];
  const int w = threadIdx.x >> 6, lane = threadIdx.x & 63;
  float s = 0.0f;
  #pragma unroll 4
  for (int i = 0; i < 32; ++i) {
    const int row = blockIdx.x * 128 + i * 4 + w;
    const int idx = bestIdx[row];
    const float4 q = *(const float4*)(c + (size_t)idx * DIM + (lane << 2));
    const float4 v = *(const float4*)(x + (size_t)row * DIM + (lane << 2));
    *(float4*)(out + (size_t)row * DIM + (lane << 2)) = q;   // x_q_out == x_q
    const float dx = q.x - v.x, dy = q.y - v.y, dz = q.z - v.z, dw = q.w - v.w;
    s += dx * dx + dy * dy + dz * dz + dw * dw;
    if (lane == 0) out[IDX_OFF + row] = (float)idx;
  }
  #pragma unroll
  for (int off = 32; off > 0; off >>= 1) s += __shfl_down(s, off);
  if (lane == 0) red[w] = s;
  __syncthreads();
  if (threadIdx.x == 0) {
    const float t = red[0] + red[1] + red[2] + red[3];
    atomicAdd(&out[LOSS_OFF], t * (1.25f / 8388608.0f));   // (1+BETA)*mean
  }
}

extern "C" void kernel_launch(void* const* d_in, const int* in_sizes, int n_in,
                              void* d_out, int out_size, void* d_ws, size_t ws_size,
                              hipStream_t stream) {
  const float* x = (const float*)d_in[0];
  const float* c = (const float*)d_in[1];
  float* out = (float*)d_out;
  char* ws = (char*)d_ws;
  _Float16* Ahi = (_Float16*)ws;
  _Float16* Bhi = (_Float16*)(ws + 16777216);
  float*    cn  = (float*)(ws + 20971520);
  float*    xn  = (float*)(ws + 21004288);
  int*  bestIdx = (int*)(ws + 21135360);
  unsigned* cand = (unsigned*)(ws + 21266432);

  vq_prep_x<<<BATCH / 4, 256, 0, stream>>>(x, Ahi, xn, out);
  vq_prep_c<<<NE / 4,    256, 0, stream>>>(c, Bhi, cn);
  vq_gemm_topk<<<256,    256, 0, stream>>>(Ahi, Bhi, cn, cand);
  vq_refine<<<BATCH / 4, 256, 0, stream>>>(cand, x, c, xn, cn, bestIdx);
  vq_finish<<<BATCH / 128, 256, 0, stream>>>(x, c, bestIdx, out);
}